// Round 2
// baseline (288.896 us; speedup 1.0000x reference)
//
#include <hip/hip_runtime.h>
#include <hip/hip_bf16.h>

// Problem sizes (fixed)
#define B_    8
#define C_    256
#define NPIX  16384           // 128*128
#define KC2   32              // K-chunks for gram
#define KCH2  (NPIX / KC2)    // 512 k per block
#define BK    64
#define NSTEP (KCH2 / BK)     // 8 steps per block

typedef __attribute__((ext_vector_type(8))) short bf16x8;
typedef __attribute__((ext_vector_type(4))) float f32x4;
typedef unsigned int uint_;

__device__ __forceinline__ unsigned short f2bf(float x) {
  unsigned int u = __builtin_bit_cast(unsigned int, x);
  u = (u + 0x7fffu + ((u >> 16) & 1u)) >> 16;   // RTNE
  return (unsigned short)u;
}

// Convert 32 staged floats (8 float4) to hi/lo bf16 (RTZ hi, RTZ lo) and
// write as 4x b128 each into swizzled LDS tile [256][64].
__device__ __forceinline__ void cvt_write(const float4* g, unsigned short* Hi,
                                          unsigned short* Lo, int srow, int shalf) {
#pragma unroll
  for (int o = 0; o < 4; ++o) {
    float f0 = g[2*o].x, f1 = g[2*o].y, f2 = g[2*o].z, f3 = g[2*o].w;
    float f4 = g[2*o+1].x, f5 = g[2*o+1].y, f6 = g[2*o+1].z, f7 = g[2*o+1].w;
    const float ff[8] = {f0,f1,f2,f3,f4,f5,f6,f7};
    uint_ hp[4], lp[4];
#pragma unroll
    for (int i = 0; i < 4; ++i) {
      uint_ u0 = __builtin_bit_cast(uint_, ff[2*i]);
      uint_ u1 = __builtin_bit_cast(uint_, ff[2*i+1]);
      hp[i] = (u0 >> 16) | (u1 & 0xffff0000u);
      float h0 = __builtin_bit_cast(float, u0 & 0xffff0000u);
      float h1 = __builtin_bit_cast(float, u1 & 0xffff0000u);
      uint_ l0 = __builtin_bit_cast(uint_, ff[2*i] - h0);
      uint_ l1 = __builtin_bit_cast(uint_, ff[2*i+1] - h1);
      lp[i] = (l0 >> 16) | (l1 & 0xffff0000u);
    }
    const int idx = (srow * 64 + shalf * 32 + o * 8) ^ ((srow & 7) << 3);
    *reinterpret_cast<uint4*>(&Hi[idx]) = make_uint4(hp[0], hp[1], hp[2], hp[3]);
    *reinterpret_cast<uint4*>(&Lo[idx]) = make_uint4(lp[0], lp[1], lp[2], lp[3]);
  }
}

// ---------------- k0: zero G ----------------
__global__ __launch_bounds__(256) void k_zero(float* __restrict__ g) {
  const size_t i = ((size_t)blockIdx.x * 256 + threadIdx.x) * 4;
  *reinterpret_cast<float4*>(g + i) = make_float4(0.f, 0.f, 0.f, 0.f);
}

// ---------------- k_gram: G[b] += X_chunk X_chunk^T (split-bf16 3-pass) -----
// grid 256 = b(8) x kc(32); 512 thr (8 waves, 2x4 grid of 128x64 tiles)
// double-buffered LDS, reg-staged prefetch, fused rowsum, atomic epilogue.
__global__ __launch_bounds__(512, 2) void k_gram(const float* __restrict__ x,
                                                 float* __restrict__ G,
                                                 float* __restrict__ spart) {
  const int bid = blockIdx.x;
  const int kc = bid & (KC2 - 1);
  const int b  = bid >> 5;
  const float* X = x + (size_t)b * C_ * NPIX + kc * KCH2;

  __shared__ __align__(16) unsigned short Hi[2][256 * 64];   // 2 x 32 KB
  __shared__ __align__(16) unsigned short Lo[2][256 * 64];   // 2 x 32 KB
  __shared__ float rsred[512];

  const int tid  = threadIdx.x;
  const int lane = tid & 63;
  const int w    = tid >> 6;
  const int wr   = w >> 2;        // 0..1  (row block of 128)
  const int wc   = w & 3;         // 0..3  (col block of 64)

  const int srow  = tid >> 1;     // staged row 0..255
  const int shalf = tid & 1;      // col half (32 f32 each)
  const float* srcrow = X + (size_t)srow * NPIX + shalf * 32;

  float rs = 0.f;
  float4 g[8];

  // prologue: stage step 0
#pragma unroll
  for (int q = 0; q < 8; ++q) g[q] = *reinterpret_cast<const float4*>(srcrow + q * 4);
#pragma unroll
  for (int q = 0; q < 8; ++q) rs += (g[q].x + g[q].y) + (g[q].z + g[q].w);
  cvt_write(g, &Hi[0][0], &Lo[0][0], srow, shalf);
  __syncthreads();

  f32x4 acc[8][4] = {};

  for (int ks = 0; ks < NSTEP; ++ks) {
    const int cur = ks & 1;
    if (ks + 1 < NSTEP) {
      const float* s2 = srcrow + (ks + 1) * BK;
#pragma unroll
      for (int q = 0; q < 8; ++q) g[q] = *reinterpret_cast<const float4*>(s2 + q * 4);
    }
    // ---- MFMA phase on buf[cur] ----
    __builtin_amdgcn_s_setprio(1);
#pragma unroll
    for (int kk = 0; kk < 2; ++kk) {
      const int kb = kk * 32 + (lane >> 4) * 8;
      bf16x8 ahi[8], bhi[4], blo[4];
#pragma unroll
      for (int m = 0; m < 8; ++m) {
        const int row = wr * 128 + m * 16 + (lane & 15);
        ahi[m] = *reinterpret_cast<const bf16x8*>(&Hi[cur][(row * 64 + kb) ^ ((row & 7) << 3)]);
      }
#pragma unroll
      for (int n = 0; n < 4; ++n) {
        const int row = wc * 64 + n * 16 + (lane & 15);
        bhi[n] = *reinterpret_cast<const bf16x8*>(&Hi[cur][(row * 64 + kb) ^ ((row & 7) << 3)]);
      }
#pragma unroll
      for (int m = 0; m < 8; ++m)
#pragma unroll
        for (int n = 0; n < 4; ++n)
          acc[m][n] = __builtin_amdgcn_mfma_f32_16x16x32_bf16(ahi[m], bhi[n], acc[m][n], 0, 0, 0);
#pragma unroll
      for (int n = 0; n < 4; ++n) {
        const int row = wc * 64 + n * 16 + (lane & 15);
        blo[n] = *reinterpret_cast<const bf16x8*>(&Lo[cur][(row * 64 + kb) ^ ((row & 7) << 3)]);
      }
#pragma unroll
      for (int m = 0; m < 8; ++m)
#pragma unroll
        for (int n = 0; n < 4; ++n)
          acc[m][n] = __builtin_amdgcn_mfma_f32_16x16x32_bf16(ahi[m], blo[n], acc[m][n], 0, 0, 0);
#pragma unroll
      for (int m = 0; m < 8; ++m) {
        const int row = wr * 128 + m * 16 + (lane & 15);
        bf16x8 alo = *reinterpret_cast<const bf16x8*>(&Lo[cur][(row * 64 + kb) ^ ((row & 7) << 3)]);
#pragma unroll
        for (int n = 0; n < 4; ++n)
          acc[m][n] = __builtin_amdgcn_mfma_f32_16x16x32_bf16(alo, bhi[n], acc[m][n], 0, 0, 0);
      }
    }
    __builtin_amdgcn_s_setprio(0);
    // ---- stage step ks+1 into buf[cur^1] (loads already in flight) ----
    if (ks + 1 < NSTEP) {
#pragma unroll
      for (int q = 0; q < 8; ++q) rs += (g[q].x + g[q].y) + (g[q].z + g[q].w);
      cvt_write(g, &Hi[cur ^ 1][0], &Lo[cur ^ 1][0], srow, shalf);
    }
    __syncthreads();
  }

  // rowsum partials
  rsred[tid] = rs;
  __syncthreads();
  if (tid < 256)
    spart[((size_t)b * KC2 + kc) * 256 + tid] = rsred[2 * tid] + rsred[2 * tid + 1];

  // atomic accumulate into G[b]
  float* Gb = G + (size_t)b * 65536;
#pragma unroll
  for (int m = 0; m < 8; ++m) {
    const int row0 = wr * 128 + m * 16 + ((lane >> 4) << 2);
#pragma unroll
    for (int n = 0; n < 4; ++n) {
      const int col = wc * 64 + n * 16 + (lane & 15);
#pragma unroll
      for (int j = 0; j < 4; ++j)
        atomicAdd(&Gb[(size_t)(row0 + j) * C_ + col], acc[m][n][j]);
    }
  }
}

// ---------------- k4: 256x256 transpose (w2 -> w2t) ----------------
__global__ __launch_bounds__(256) void k_transpose(const float* __restrict__ in,
                                                   float* __restrict__ outp) {
  __shared__ float t[32][33];
  const int bx = blockIdx.x & 7, by = blockIdx.x >> 3;
  const int tx = threadIdx.x & 31, ty = threadIdx.x >> 5;
#pragma unroll
  for (int i = 0; i < 32; i += 8)
    t[ty + i][tx] = in[(size_t)(by * 32 + ty + i) * 256 + bx * 32 + tx];
  __syncthreads();
#pragma unroll
  for (int i = 0; i < 32; i += 8)
    outp[(size_t)(bx * 32 + ty + i) * 256 + by * 32 + tx] = t[tx][ty + i];
}

// ---------------- k_u: s = reduce(spart); u1 = W1 s, u2 = W2 s ----------------
__global__ __launch_bounds__(256) void k_u(const float* __restrict__ w1,
                                           const float* __restrict__ w2,
                                           const float* __restrict__ spart,
                                           float* __restrict__ u1,
                                           float* __restrict__ u2) {
  const int b = blockIdx.x;
  const int tid = threadIdx.x;
  __shared__ float sl[256];
  float sv = 0.f;
#pragma unroll 8
  for (int kc = 0; kc < KC2; ++kc) sv += spart[((size_t)b * KC2 + kc) * 256 + tid];
  sl[tid] = sv;
  __syncthreads();
  float a1 = 0.f, a2 = 0.f;
#pragma unroll 4
  for (int c = 0; c < 256; ++c) {
    a1 += w1[(size_t)tid * 256 + c] * sl[c];
    a2 += w2[(size_t)tid * 256 + c] * sl[c];
  }
  u1[b * 256 + tid] = a1;
  u2[b * 256 + tid] = a2;
}

// ---------------- k_smallmm: C[i,j] = sum_k A[i,k] B[k,j] (256^3) ----------
__global__ __launch_bounds__(256) void k_smallmm(const float* __restrict__ A, long asb,
                                                 const float* __restrict__ Bm, long bsb,
                                                 float* __restrict__ Cm, long csb) {
  const int b  = blockIdx.y;
  const int i0 = blockIdx.x * 8;
  const float* Ab = A  + (size_t)asb * b;
  const float* Bb = Bm + (size_t)bsb * b;
  float*       Cb = Cm + (size_t)csb * b;
  const int tid = threadIdx.x;
  __shared__ float arows[8][256];
#pragma unroll
  for (int rr = 0; rr < 8; ++rr) arows[rr][tid] = Ab[(size_t)(i0 + rr) * 256 + tid];
  __syncthreads();
  float acc[8] = {};
#pragma unroll 4
  for (int k = 0; k < 256; ++k) {
    const float bv = Bb[(size_t)k * 256 + tid];
#pragma unroll
    for (int rr = 0; rr < 8; ++rr) acc[rr] += arows[rr][k] * bv;
  }
#pragma unroll
  for (int rr = 0; rr < 8; ++rr) Cb[(size_t)(i0 + rr) * 256 + tid] = acc[rr];
}

// ---------------- k_softmax: logits finish + row softmax -> A (bf16) --------
__global__ __launch_bounds__(256) void k_softmax(const float* __restrict__ L,
                                                 const float* __restrict__ b1,
                                                 const float* __restrict__ b2,
                                                 const float* __restrict__ u1,
                                                 const float* __restrict__ u2,
                                                 unsigned short* __restrict__ Abf) {
  const int b = blockIdx.y, i = blockIdx.x, j = threadIdx.x;
  const size_t base = ((size_t)b * 256 + i) * 256;
  const float v = L[base + j] + u1[b * 256 + i] * b2[j] +
                  b1[i] * (u2[b * 256 + j] + 16384.f * b2[j]);
  const int lane = j & 63, wv = j >> 6;
  __shared__ float redm[4], reds[4];
  float m = v;
#pragma unroll
  for (int off = 32; off; off >>= 1) m = fmaxf(m, __shfl_xor(m, off, 64));
  if (lane == 0) redm[wv] = m;
  __syncthreads();
  m = fmaxf(fmaxf(redm[0], redm[1]), fmaxf(redm[2], redm[3]));
  const float e = __expf(v - m);
  float sm = e;
#pragma unroll
  for (int off = 32; off; off >>= 1) sm += __shfl_xor(sm, off, 64);
  if (lane == 0) reds[wv] = sm;
  __syncthreads();
  sm = (reds[0] + reds[1]) + (reds[2] + reds[3]);
  Abf[base + j] = f2bf(e / sm);
}

// ---------------- k_av: out = x + A @ X  (A-frags direct from L2) ----------
// grid 2048 = n-tile(256) x b(8, low bits -> XCD-pinned); 512 thr (8 waves)
// wave grid 4(c) x 2(n): tile 64x32. Xt staged once in LDS (32 KB).
__global__ __launch_bounds__(512, 4) void k_av(const unsigned short* __restrict__ Abf,
                                               const float* __restrict__ x,
                                               float* __restrict__ out) {
  const int bx = blockIdx.x;
  const int b  = bx & 7;
  const int n0 = (bx >> 3) * 64;
  const unsigned short* Ab = Abf + (size_t)b * 65536;
  const float* Xb = x   + (size_t)b * C_ * NPIX;
  float*       Ob = out + (size_t)b * C_ * NPIX;

  __shared__ __align__(16) unsigned short Xt[64 * 256];   // [n][d] swizzled, 32 KB

  const int tid = threadIdx.x;
  const int lane = tid & 63, w = tid >> 6;
  const int wc2 = w >> 1, wn = w & 1;

  // stage X^T (bf16, RTNE) once: two 4x4 blocks per thread
#pragma unroll
  for (int h = 0; h < 2; ++h) {
    const int d  = (tid >> 4) * 4 + h * 128;
    const int nn = (tid & 15) * 4;
    const float* xs = Xb + (size_t)d * NPIX + n0 + nn;
    float4 r0 = *reinterpret_cast<const float4*>(xs);
    float4 r1 = *reinterpret_cast<const float4*>(xs + NPIX);
    float4 r2 = *reinterpret_cast<const float4*>(xs + 2 * NPIX);
    float4 r3 = *reinterpret_cast<const float4*>(xs + 3 * NPIX);
    ushort4 c0 = make_ushort4(f2bf(r0.x), f2bf(r1.x), f2bf(r2.x), f2bf(r3.x));
    ushort4 c1 = make_ushort4(f2bf(r0.y), f2bf(r1.y), f2bf(r2.y), f2bf(r3.y));
    ushort4 c2 = make_ushort4(f2bf(r0.z), f2bf(r1.z), f2bf(r2.z), f2bf(r3.z));
    ushort4 c3 = make_ushort4(f2bf(r0.w), f2bf(r1.w), f2bf(r2.w), f2bf(r3.w));
    const int i0 = ((nn + 0) * 256 + d) ^ (((nn + 0) & 7) << 3);
    const int i1 = ((nn + 1) * 256 + d) ^ (((nn + 1) & 7) << 3);
    const int i2 = ((nn + 2) * 256 + d) ^ (((nn + 2) & 7) << 3);
    const int i3 = ((nn + 3) * 256 + d) ^ (((nn + 3) & 7) << 3);
    *reinterpret_cast<ushort4*>(&Xt[i0]) = c0;
    *reinterpret_cast<ushort4*>(&Xt[i1]) = c1;
    *reinterpret_cast<ushort4*>(&Xt[i2]) = c2;
    *reinterpret_cast<ushort4*>(&Xt[i3]) = c3;
  }
  __syncthreads();

  f32x4 acc[4][2] = {};
#pragma unroll
  for (int kk = 0; kk < 8; ++kk) {
    const int kb = kk * 32 + (lane >> 4) * 8;
    bf16x8 af[4], bq[2];
#pragma unroll
    for (int m = 0; m < 4; ++m) {
      const int c = wc2 * 64 + m * 16 + (lane & 15);
      uint4 v = *reinterpret_cast<const uint4*>(Ab + (size_t)c * 256 + kb);
      af[m] = __builtin_bit_cast(bf16x8, v);
    }
#pragma unroll
    for (int n = 0; n < 2; ++n) {
      const int nn = wn * 32 + n * 16 + (lane & 15);
      bq[n] = *reinterpret_cast<const bf16x8*>(&Xt[(nn * 256 + kb) ^ ((nn & 7) << 3)]);
    }
#pragma unroll
    for (int m = 0; m < 4; ++m)
#pragma unroll
      for (int n = 0; n < 2; ++n)
        acc[m][n] = __builtin_amdgcn_mfma_f32_16x16x32_bf16(af[m], bq[n], acc[m][n], 0, 0, 0);
  }

  // epilogue: out = x + acc (x re-read is L2-hot: same 64 KB staged above)
#pragma unroll
  for (int m = 0; m < 4; ++m) {
    const int row0 = wc2 * 64 + m * 16 + ((lane >> 4) << 2);
#pragma unroll
    for (int n = 0; n < 2; ++n) {
      const int col = n0 + wn * 32 + n * 16 + (lane & 15);
#pragma unroll
      for (int j = 0; j < 4; ++j) {
        const size_t a = (size_t)(row0 + j) * NPIX + col;
        Ob[a] = Xb[a] + acc[m][n][j];
      }
    }
  }
}

extern "C" void kernel_launch(void* const* d_in, const int* in_sizes, int n_in,
                              void* d_out, int out_size, void* d_ws, size_t ws_size,
                              hipStream_t stream) {
  const float* x  = (const float*)d_in[0];
  const float* w1 = (const float*)d_in[1];
  const float* b1 = (const float*)d_in[2];
  const float* w2 = (const float*)d_in[3];
  const float* b2 = (const float*)d_in[4];
  float* out = (float*)d_out;
  char* ws = (char*)d_ws;

  // ws layout (bytes); total ~7.6 MB
  constexpr size_t G_OFF     = 0;                                   // 2 MB
  constexpr size_t T1_OFF    = G_OFF   + (size_t)B_ * C_ * C_ * 4;  // 2 MB
  constexpr size_t L_OFF     = T1_OFF  + (size_t)B_ * C_ * C_ * 4;  // 2 MB
  constexpr size_t W2T_OFF   = L_OFF   + (size_t)B_ * C_ * C_ * 4;  // 256 KB
  constexpr size_t SPART_OFF = W2T_OFF + (size_t)C_ * C_ * 4;       // 256 KB
  constexpr size_t U1_OFF    = SPART_OFF + (size_t)B_ * KC2 * C_ * 4;
  constexpr size_t U2_OFF    = U1_OFF  + (size_t)B_ * C_ * 4;
  constexpr size_t ABF_OFF   = U2_OFF  + (size_t)B_ * C_ * 4;       // 1 MB

  float* G     = (float*)(ws + G_OFF);
  float* T1    = (float*)(ws + T1_OFF);
  float* L     = (float*)(ws + L_OFF);
  float* w2t   = (float*)(ws + W2T_OFF);
  float* spart = (float*)(ws + SPART_OFF);
  float* u1    = (float*)(ws + U1_OFF);
  float* u2    = (float*)(ws + U2_OFF);
  unsigned short* Abf = (unsigned short*)(ws + ABF_OFF);

  k_zero     <<<(B_ * C_ * C_) / 1024, 256, 0, stream>>>(G);
  k_transpose<<<64, 256, 0, stream>>>(w2, w2t);
  k_gram     <<<B_ * KC2, 512, 0, stream>>>(x, G, spart);
  k_u        <<<B_, 256, 0, stream>>>(w1, w2, spart, u1, u2);
  // T1 = W1 @ G   (A unbatched, B/C batched)
  k_smallmm  <<<dim3(32, B_), 256, 0, stream>>>(w1, 0, G, C_ * C_, T1, C_ * C_);
  // L = T1 @ W2^T = T1 @ w2t  (A/C batched, B unbatched)
  k_smallmm  <<<dim3(32, B_), 256, 0, stream>>>(T1, C_ * C_, w2t, 0, L, C_ * C_);
  k_softmax  <<<dim3(C_, B_), 256, 0, stream>>>(L, b1, b2, u1, u2, Abf);
  k_av       <<<dim3(NPIX / 64 * B_), 512, 0, stream>>>(Abf, x, out);
}